// Round 8
// baseline (121.205 us; speedup 1.0000x reference)
//
#include <hip/hip_runtime.h>
#include <math.h>

// Problem constants (reference: N=256, S=1, stimulus 144x256, retina 144x256)
#define NB    256
#define IMG_H 144
#define IMG_W 256
#define IMG_ELEMS (IMG_H * IMG_W)   // 36864 px
#define FDIM  16
#define DDIM  128

// fp16 LDS layout: 1-px zero border all around, padded row stride.
// Row stride 264 halves = 132 dwords; 132 % 32 = 4 -> adjacent rows offset
// 4 banks (no systematic v00/v10 collision). Image x=i lives at half-index
// i+4 (8B-aligned staging writes); left border zeros at [0..3], right at
// [260..263]. Rows: image y=r at row r+1; rows 0 and 145 are zero borders.
// Total 146*264*2B = 77,088 B -> TWO blocks fit in 160 KiB -> 32 waves/CU.
#define LDS_STRIDE_H 264
#define LDS_ROWS     (IMG_H + 2)
#define SIDE_CELLS   (IMG_H * 8)    // 1152 side-border halves (> 1024 threads!)

#define FOV_HALF_RAD 0.6544984694978736f   // 0.5 * 75deg in rad
#define GELU_GAMMA   1.7015043497085571f
#define OUT_OF_RANGE 10.0f

typedef float    f32x4 __attribute__((ext_vector_type(4)));
typedef _Float16 f16x4 __attribute__((ext_vector_type(4)));

// jax.nn.gelu default is approximate=True (tanh form)
__device__ __forceinline__ float gelu_gamma(float x) {
    const float k0 = 0.7978845608028654f;  // sqrt(2/pi)
    const float k1 = 0.044715f;
    float t = tanhf(k0 * (x + k1 * x * x * x));
    return 0.5f * x * (1.0f + t) * GELU_GAMMA;
}

// One block per batch element; 128 threads = hidden dim.
__global__ void __launch_bounds__(DDIM) mlp_rmat_kernel(
    const float* __restrict__ persp,  // [NB, FDIM]
    const float* __restrict__ W1,     // [FDIM, DDIM]
    const float* __restrict__ b1,     // [DDIM]
    const float* __restrict__ W2,     // [DDIM, DDIM]
    const float* __restrict__ b2,     // [DDIM]
    const float* __restrict__ Wp,     // [DDIM, 3]
    const float* __restrict__ bp,     // [3]
    float* __restrict__ Rout)         // [NB, 9]
{
    const int n = blockIdx.x;
    const int d = threadIdx.x;

    __shared__ float sh1[DDIM];
    __shared__ float sh2[DDIM];
    __shared__ float ang[3];

    float acc = b1[d];
#pragma unroll
    for (int f = 0; f < FDIM; ++f)
        acc += persp[n * FDIM + f] * W1[f * DDIM + d];
    sh1[d] = gelu_gamma(acc);
    __syncthreads();

    float acc2 = b2[d];
#pragma unroll 8
    for (int k = 0; k < DDIM; ++k)
        acc2 += sh1[k] * W2[k * DDIM + d];
    sh2[d] = gelu_gamma(acc2);
    __syncthreads();

    if (d < 3) {
        float a = bp[d];
#pragma unroll 8
        for (int k = 0; k < DDIM; ++k)
            a += sh2[k] * Wp[k * 3 + d];
        ang[d] = a;
    }
    __syncthreads();

    if (d == 0) {
        float cx = cosf(ang[0]), sx = sinf(ang[0]);
        float cy = cosf(ang[1]), sy = sinf(ang[1]);
        float cz = cosf(ang[2]), sz = sinf(ang[2]);
        float* R = Rout + n * 9;
        R[0] = cz * cy;  R[1] = cz * sy * sx - sz * cx;  R[2] = cz * sy * cx + sz * sx;
        R[3] = sz * cy;  R[4] = sz * sy * sx + cz * cx;  R[5] = sz * sy * cx - cz * sx;
        R[6] = -sy;      R[7] = cy * sx;                 R[8] = cy * cx;
    }
}

// grid (NB, 2): block (n, half) stages the FULL image n into fp16 LDS
// (75.3 KiB -> 2 blocks/CU, 32 waves/CU) and computes half the output px.
// Zero border + coordinate clamp to [-1,256]x[-1,144] replaces all OOB
// masks: every invalid corner reads a real 0 from the border.
__global__ void __launch_bounds__(1024, 8) retina_sample_kernel(
    const float* __restrict__ stim,   // [NB, 1, IMG_H, IMG_W]
    const float* __restrict__ Rmat,   // [NB, 9]
    float* __restrict__ out)          // [NB, 1, IMG_H, IMG_W]
{
    __shared__ _Float16 simg[LDS_ROWS * LDS_STRIDE_H];   // 77,088 B

    const int tid  = threadIdx.x;
    const int n    = blockIdx.x;
    const int half = blockIdx.y;

    // Block-uniform rotation matrix (scalar loads)
    const float* Rn = Rmat + n * 9;
    const float r0 = Rn[0], r1 = Rn[1], r2 = Rn[2];
    const float r3 = Rn[3], r4 = Rn[4], r5 = Rn[5];
    const float r6 = Rn[6], r7 = Rn[7], r8 = Rn[8];

    const float* __restrict__ img = stim + (size_t)n * IMG_ELEMS;

    // ---- zero the border
    // top row 0 + bottom row 145 (264 halves each)
    if (tid < LDS_STRIDE_H) {
        simg[tid] = (_Float16)0.0f;
        simg[(LDS_ROWS - 1) * LDS_STRIDE_H + tid] = (_Float16)0.0f;
    }
    // side borders: 1152 cells > 1024 threads -> STRIDED loop (R7 bug: the
    // single `if (tid < 1152)` left cells 1024..1151 = rows 129..144
    // uninitialized -> NaN garbage reads)
    for (int sb = tid; sb < SIDE_CELLS; sb += 1024) {
        const int r = (sb >> 3) + 1;        // 1..144
        int c = sb & 7;                     // 0..7
        c = (c < 4) ? c : (c + 256);        // {0..3} or {260..263}
        simg[r * LDS_STRIDE_H + c] = (_Float16)0.0f;
    }

    // ---- stage full image -> fp16 LDS: 9216 f32x4 groups, 9 per thread
    {
        const f32x4* __restrict__ src = (const f32x4*)img;
#pragma unroll
        for (int p = 0; p < 9; ++p) {
            const int g   = tid + p * 1024;   // f32x4-group index
            const int row = g >> 6;           // 64 groups per image row
            const int c4  = g & 63;
            const f16x4 hv = __builtin_convertvector(src[g], f16x4);
            *(f16x4*)&simg[(row + 1) * LDS_STRIDE_H + 4 + c4 * 4] = hv;
        }
    }
    __syncthreads();

    // ---- gather: this block covers px [half*18432, half*18432+18432)
    //      = 4608 f32x4-groups over 1024 threads -> 4.5 iterations
#pragma unroll
    for (int p = 0; p < 5; ++p) {
        const int gg = p * 1024 + tid;
        if (gg >= 4608) break;               // only tid<512 run p=4
        const int px0 = half * 18432 + gg * 4;
        const int h   = px0 >> 8;
        const int w0  = px0 & 255;

        // per-row constants
        const float gy  = (2.0f * h + 1.0f - 144.0f) * (1.0f / 256.0f);
        const float ayv = gy * FOV_HALF_RAD;
        const float ay2 = ayv * ayv;
        const float bx = ayv * r1, by = ayv * r4, bz = ayv * r7;

        float wx_[4], wy_[4];
        int a00[4], a01[4], a10[4], a11[4];

#pragma unroll
        for (int j = 0; j < 4; ++j) {
            // ax = ((2w+1-256)/256)*FOV  ->  linear in w
            const float ax = fmaf((float)(w0 + j),
                                  2.0f * FOV_HALF_RAD * (1.0f / 256.0f),
                                  -255.0f * FOV_HALF_RAD * (1.0f / 256.0f));
            const float t = fmaf(ax, ax, ay2);          // a^2, t <= 0.56

            // sinc(a): even Taylor in t, |err| ~1e-8 on this range
            float sc = fmaf(t, 2.7557319e-6f, -1.9841270e-4f);
            sc = fmaf(t, sc,  8.3333333e-3f);
            sc = fmaf(t, sc, -1.6666667e-1f);
            sc = fmaf(t, sc,  1.0f);

            // cos(a): even Taylor in t
            float ca = fmaf(t, 2.4801587e-5f, -1.3888889e-3f);
            ca = fmaf(t, ca,  4.1666667e-2f);
            ca = fmaf(t, ca, -0.5f);
            ca = fmaf(t, ca,  1.0f);

            // rotated ray, row-hoisted: r* = sc*(ax*rC + ayv*rC') + ca*rC''
            const float rx = fmaf(ca, r2, sc * fmaf(ax, r0, bx));
            const float ry = fmaf(ca, r5, sc * fmaf(ax, r3, by));
            const float rz = fmaf(ca, r8, sc * fmaf(ax, r6, bz));

            const float inv = __builtin_amdgcn_rcpf(rz);
            const bool safe = rz > 0.001f;
            const float gxp = safe ? rx * inv : OUT_OF_RANGE;
            const float gyp = safe ? ry * inv : OUT_OF_RANGE;

            const float px = fmaf(gxp, 128.0f, 127.5f);  // (gxp*256+255)*0.5
            const float py = fmaf(gyp, 128.0f, 71.5f);   // (gyp*256+143)*0.5

            const float x0f = floorf(px), y0f = floorf(py);
            wx_[j] = px - x0f;
            wy_[j] = py - y0f;
            const int x0 = (int)x0f, y0 = (int)y0f;

            // clamp into bordered region: OOB corners land on zero border
            const int xc0 = min(max(x0,     -1), 256);
            const int xc1 = min(max(x0 + 1, -1), 256);
            const int yc0 = min(max(y0,     -1), 144);
            const int yc1 = min(max(y0 + 1, -1), 144);

            const int row0 = yc0 * LDS_STRIDE_H + (LDS_STRIDE_H + 4);
            const int row1 = yc1 * LDS_STRIDE_H + (LDS_STRIDE_H + 4);
            a00[j] = row0 + xc0;  a01[j] = row0 + xc1;
            a10[j] = row1 + xc0;  a11[j] = row1 + xc1;
        }

        // issue all 16 LDS reads back-to-back
        float v00[4], v01[4], v10[4], v11[4];
#pragma unroll
        for (int j = 0; j < 4; ++j) {
            v00[j] = (float)simg[a00[j]];
            v01[j] = (float)simg[a01[j]];
            v10[j] = (float)simg[a10[j]];
            v11[j] = (float)simg[a11[j]];
        }

        f32x4 res;
#pragma unroll
        for (int j = 0; j < 4; ++j) {
            const float top = fmaf(wx_[j], v01[j] - v00[j], v00[j]);
            const float bot = fmaf(wx_[j], v11[j] - v10[j], v10[j]);
            res[j] = fmaf(wy_[j], bot - top, top);
        }

        f32x4* dst = (f32x4*)(out + (size_t)n * IMG_ELEMS + px0);
        __builtin_nontemporal_store(res, dst);
    }
}

extern "C" void kernel_launch(void* const* d_in, const int* in_sizes, int n_in,
                              void* d_out, int out_size, void* d_ws, size_t ws_size,
                              hipStream_t stream) {
    const float* stimulus    = (const float*)d_in[0]; // [256,1,144,256]
    const float* perspective = (const float*)d_in[1]; // [256,16]
    const float* W1          = (const float*)d_in[2]; // [16,128]
    const float* b1          = (const float*)d_in[3]; // [128]
    const float* W2          = (const float*)d_in[4]; // [128,128]
    const float* b2          = (const float*)d_in[5]; // [128]
    const float* Wp          = (const float*)d_in[6]; // [128,3]
    const float* bp          = (const float*)d_in[7]; // [3]
    float* out = (float*)d_out;

    float* Rmat = (float*)d_ws; // 256*9 floats

    mlp_rmat_kernel<<<NB, DDIM, 0, stream>>>(
        perspective, W1, b1, W2, b2, Wp, bp, Rmat);

    dim3 grid(NB, 2);
    retina_sample_kernel<<<grid, 1024, 0, stream>>>(stimulus, Rmat, out);
}

// Round 9
// 120.231 us; speedup vs baseline: 1.0081x; 1.0081x over previous
//
#include <hip/hip_runtime.h>
#include <math.h>

// Problem constants (reference: N=256, S=1, stimulus 144x256, retina 144x256)
#define NB    256
#define IMG_H 144
#define IMG_W 256
#define IMG_ELEMS (IMG_H * IMG_W)   // 36864 px
#define FDIM  16
#define DDIM  128

// fp16 LDS layout, clamp-free gather:
//   coordinate trick: pxs = clamp(px+1, 0, 257), x0s = trunc(pxs) -> x0 = x0s-1
//   covers x in [-1,257]; col = x + 4 -> cols 3..261. Zero cells: cols 0..3 and
//   260..263 (sides), rows 0, 145, 146 (top + 2 bottom: y in [-1,145]).
//   Row stride 264 halves = 132 dwords; 132 % 32 = 4 -> adjacent rows offset
//   4 banks. Total 147*264*2 = 77,616 B -> two blocks/CU.
#define LDS_STRIDE_H 264
#define LDS_ROWS     (IMG_H + 3)     // rows 0..146
#define BORDER_CELLS (3 * LDS_STRIDE_H + IMG_H * 8)   // 792 + 1152 = 1944

#define FOV_HALF_RAD 0.6544984694978736f   // 0.5 * 75deg in rad
#define GELU_GAMMA   1.7015043497085571f
#define OUT_OF_RANGE 10.0f

typedef float    f32x4 __attribute__((ext_vector_type(4)));
typedef _Float16 f16x4 __attribute__((ext_vector_type(4)));
typedef _Float16 f16x2 __attribute__((ext_vector_type(2)));

// jax.nn.gelu default is approximate=True (tanh form)
__device__ __forceinline__ float gelu_gamma(float x) {
    const float k0 = 0.7978845608028654f;  // sqrt(2/pi)
    const float k1 = 0.044715f;
    float t = tanhf(k0 * (x + k1 * x * x * x));
    return 0.5f * x * (1.0f + t) * GELU_GAMMA;
}

// One block per batch element; 128 threads = hidden dim.
__global__ void __launch_bounds__(DDIM) mlp_rmat_kernel(
    const float* __restrict__ persp,  // [NB, FDIM]
    const float* __restrict__ W1,     // [FDIM, DDIM]
    const float* __restrict__ b1,     // [DDIM]
    const float* __restrict__ W2,     // [DDIM, DDIM]
    const float* __restrict__ b2,     // [DDIM]
    const float* __restrict__ Wp,     // [DDIM, 3]
    const float* __restrict__ bp,     // [3]
    float* __restrict__ Rout)         // [NB, 9]
{
    const int n = blockIdx.x;
    const int d = threadIdx.x;

    __shared__ float sh1[DDIM];
    __shared__ float sh2[DDIM];
    __shared__ float ang[3];

    float acc = b1[d];
#pragma unroll
    for (int f = 0; f < FDIM; ++f)
        acc += persp[n * FDIM + f] * W1[f * DDIM + d];
    sh1[d] = gelu_gamma(acc);
    __syncthreads();

    float acc2 = b2[d];
#pragma unroll 8
    for (int k = 0; k < DDIM; ++k)
        acc2 += sh1[k] * W2[k * DDIM + d];
    sh2[d] = gelu_gamma(acc2);
    __syncthreads();

    if (d < 3) {
        float a = bp[d];
#pragma unroll 8
        for (int k = 0; k < DDIM; ++k)
            a += sh2[k] * Wp[k * 3 + d];
        ang[d] = a;
    }
    __syncthreads();

    if (d == 0) {
        float cx = cosf(ang[0]), sx = sinf(ang[0]);
        float cy = cosf(ang[1]), sy = sinf(ang[1]);
        float cz = cosf(ang[2]), sz = sinf(ang[2]);
        float* R = Rout + n * 9;
        R[0] = cz * cy;  R[1] = cz * sy * sx - sz * cx;  R[2] = cz * sy * cx + sz * sx;
        R[3] = sz * cy;  R[4] = sz * sy * sx + cz * cx;  R[5] = sz * sy * cx - cz * sx;
        R[6] = -sy;      R[7] = cy * sx;                 R[8] = cy * cx;
    }
}

// grid (NB, 2): block (n, half) stages the FULL image n into fp16 LDS and
// computes half the output pixels. Same-XCD pairing (ids n and 256+n are both
// n%8) means the second block's stage re-read hits L2.
__global__ void __launch_bounds__(1024, 8) retina_sample_kernel(
    const float* __restrict__ stim,   // [NB, 1, IMG_H, IMG_W]
    const float* __restrict__ Rmat,   // [NB, 9]
    float* __restrict__ out)          // [NB, 1, IMG_H, IMG_W]
{
    __shared__ __align__(16) _Float16 simg[LDS_ROWS * LDS_STRIDE_H];

    const int tid  = threadIdx.x;
    const int n    = blockIdx.x;
    const int half = blockIdx.y;

    // Block-uniform rotation matrix (scalar loads)
    const float* Rn = Rmat + n * 9;
    const float r0 = Rn[0], r1 = Rn[1], r2 = Rn[2];
    const float r3 = Rn[3], r4 = Rn[4], r5 = Rn[5];
    const float r6 = Rn[6], r7 = Rn[7], r8 = Rn[8];

    const float* __restrict__ img = stim + (size_t)n * IMG_ELEMS;

    // ---- zero the border: 1944 cells, strided (disjoint from image cells,
    //      so the single pre-gather barrier suffices)
    for (int i = tid; i < BORDER_CELLS; i += 1024) {
        int idx;
        if (i < 3 * LDS_STRIDE_H) {
            const int r3_ = i / LDS_STRIDE_H;            // 0,1,2
            const int c   = i - r3_ * LDS_STRIDE_H;
            const int r   = (r3_ == 0) ? 0 : (IMG_H + r3_);  // 0,145,146
            idx = r * LDS_STRIDE_H + c;
        } else {
            const int j = i - 3 * LDS_STRIDE_H;          // 0..1151
            const int r = 1 + (j >> 3);                  // 1..144
            int c = j & 7;
            c = (c < 4) ? c : (c + 256);                 // {0..3} / {260..263}
            idx = r * LDS_STRIDE_H + c;
        }
        simg[idx] = (_Float16)0.0f;
    }

    // ---- stage full image -> fp16 LDS: 9216 f32x4 groups, 9 per thread
    {
        const f32x4* __restrict__ src = (const f32x4*)img;
#pragma unroll
        for (int p = 0; p < 9; ++p) {
            const int g   = tid + p * 1024;   // f32x4-group index
            const int row = g >> 6;           // 64 groups per image row
            const int c4  = g & 63;
            const f16x4 hv = __builtin_convertvector(src[g], f16x4);
            *(f16x4*)&simg[(row + 1) * LDS_STRIDE_H + 4 + c4 * 4] = hv;
        }
    }
    __syncthreads();

    const unsigned* __restrict__ U = (const unsigned*)simg;   // dword view

    // ---- gather: this block covers px [half*18432, half*18432+18432)
#pragma unroll
    for (int p = 0; p < 5; ++p) {
        const int gg = p * 1024 + tid;
        if (gg >= 4608) break;               // wave-uniform tail (tid<512 on p=4)
        const int px0 = half * 18432 + gg * 4;
        const int h   = px0 >> 8;
        const int w0  = px0 & 255;

        // per-row constants
        const float gy  = (2.0f * h + 1.0f - 144.0f) * (1.0f / 256.0f);
        const float ayv = gy * FOV_HALF_RAD;
        const float ay2 = ayv * ayv;
        const float bx = ayv * r1, by = ayv * r4, bz = ayv * r7;

        float wx_[4], wy_[4];
        int dA[4];
        unsigned sh_[4];

#pragma unroll
        for (int j = 0; j < 4; ++j) {
            // ax linear in w
            const float ax = fmaf((float)(w0 + j),
                                  2.0f * FOV_HALF_RAD * (1.0f / 256.0f),
                                  -255.0f * FOV_HALF_RAD * (1.0f / 256.0f));
            const float t = fmaf(ax, ax, ay2);          // a^2, t <= 0.56

            // sinc(a): even Taylor in t
            float sc = fmaf(t, 2.7557319e-6f, -1.9841270e-4f);
            sc = fmaf(t, sc,  8.3333333e-3f);
            sc = fmaf(t, sc, -1.6666667e-1f);
            sc = fmaf(t, sc,  1.0f);

            // cos(a): even Taylor in t
            float ca = fmaf(t, 2.4801587e-5f, -1.3888889e-3f);
            ca = fmaf(t, ca,  4.1666667e-2f);
            ca = fmaf(t, ca, -0.5f);
            ca = fmaf(t, ca,  1.0f);

            const float rx = fmaf(ca, r2, sc * fmaf(ax, r0, bx));
            const float ry = fmaf(ca, r5, sc * fmaf(ax, r3, by));
            const float rz = fmaf(ca, r8, sc * fmaf(ax, r6, bz));

            const float inv = __builtin_amdgcn_rcpf(rz);
            const bool safe = rz > 0.001f;
            const float gxp = safe ? rx * inv : OUT_OF_RANGE;
            const float gyp = safe ? ry * inv : OUT_OF_RANGE;

            // shifted coords: pxs = px+1 in [0,257], pys = py+1 in [0,145]
            const float pxs = __builtin_amdgcn_fmed3f(
                fmaf(gxp, 128.0f, 128.5f), 0.0f, 257.0f);
            const float pys = __builtin_amdgcn_fmed3f(
                fmaf(gyp, 128.0f, 72.5f), 0.0f, 145.0f);

            const int x0s = (int)pxs;        // trunc == floor (>=0)
            const int y0s = (int)pys;
            wx_[j] = pxs - (float)x0s;
            wy_[j] = pys - (float)y0s;

            // half-index of corner00: row y0s, col x0s+3
            const int a00 = y0s * LDS_STRIDE_H + x0s + 3;
            dA[j]  = a00 >> 1;
            sh_[j] = (unsigned)(a00 & 1) << 4;
        }

        // 4 dword reads per px (2x ds_read2_b32), all issued back-to-back
        unsigned u[16];
#pragma unroll
        for (int j = 0; j < 4; ++j) {
            u[4*j+0] = U[dA[j]];
            u[4*j+1] = U[dA[j] + 1];
            u[4*j+2] = U[dA[j] + 132];    // +1 row (264 halves = 132 dwords)
            u[4*j+3] = U[dA[j] + 133];
        }

        f32x4 res;
#pragma unroll
        for (int j = 0; j < 4; ++j) {
            const unsigned long long t0 =
                ((unsigned long long)u[4*j+1] << 32) | u[4*j+0];
            const unsigned long long t1 =
                ((unsigned long long)u[4*j+3] << 32) | u[4*j+2];
            const f16x2 h0 = __builtin_bit_cast(f16x2, (unsigned)(t0 >> sh_[j]));
            const f16x2 h1 = __builtin_bit_cast(f16x2, (unsigned)(t1 >> sh_[j]));
            const float v00 = (float)h0[0], v01 = (float)h0[1];
            const float v10 = (float)h1[0], v11 = (float)h1[1];
            const float top = fmaf(wx_[j], v01 - v00, v00);
            const float bot = fmaf(wx_[j], v11 - v10, v10);
            res[j] = fmaf(wy_[j], bot - top, top);
        }

        f32x4* dst = (f32x4*)(out + (size_t)n * IMG_ELEMS + px0);
        __builtin_nontemporal_store(res, dst);
    }
}

extern "C" void kernel_launch(void* const* d_in, const int* in_sizes, int n_in,
                              void* d_out, int out_size, void* d_ws, size_t ws_size,
                              hipStream_t stream) {
    const float* stimulus    = (const float*)d_in[0]; // [256,1,144,256]
    const float* perspective = (const float*)d_in[1]; // [256,16]
    const float* W1          = (const float*)d_in[2]; // [16,128]
    const float* b1          = (const float*)d_in[3]; // [128]
    const float* W2          = (const float*)d_in[4]; // [128,128]
    const float* b2          = (const float*)d_in[5]; // [128]
    const float* Wp          = (const float*)d_in[6]; // [128,3]
    const float* bp          = (const float*)d_in[7]; // [3]
    float* out = (float*)d_out;

    float* Rmat = (float*)d_ws; // 256*9 floats

    mlp_rmat_kernel<<<NB, DDIM, 0, stream>>>(
        perspective, W1, b1, W2, b2, Wp, bp, Rmat);

    dim3 grid(NB, 2);
    retina_sample_kernel<<<grid, 1024, 0, stream>>>(stimulus, Rmat, out);
}

// Round 10
// 119.319 us; speedup vs baseline: 1.0158x; 1.0076x over previous
//
#include <hip/hip_runtime.h>
#include <math.h>

// Problem constants (reference: N=256, S=1, stimulus 144x256, retina 144x256)
#define NB    256
#define IMG_H 144
#define IMG_W 256
#define IMG_ELEMS (IMG_H * IMG_W)   // 36864 px
#define FDIM  16
#define DDIM  128

// fp16 LDS layout, clamp-free gather (validated in R8/R9):
//   pxs = clamp(px+1, 0, 257), x0s = trunc -> x0 = x0s-1 in [-1,256];
//   col = x+4 -> 3..260. Zero cells: cols 0..3 / 260..263, rows 0,145,146.
//   Row stride 264 halves = 132 dwords; 132 % 32 = 4 -> adjacent rows offset
//   4 banks. simg = 147*264*2 = 77,616 B; + 1,072 B MLP scratch -> two
//   blocks/CU still fit in 160 KiB.
#define LDS_STRIDE_H 264
#define LDS_ROWS     (IMG_H + 3)     // rows 0..146
#define BORDER_CELLS (3 * LDS_STRIDE_H + IMG_H * 8)   // 792 + 1152 = 1944

#define FOV_HALF_RAD 0.6544984694978736f   // 0.5 * 75deg in rad
#define GELU_GAMMA   1.7015043497085571f
#define OUT_OF_RANGE 10.0f

typedef float    f32x4 __attribute__((ext_vector_type(4)));
typedef _Float16 f16x4 __attribute__((ext_vector_type(4)));
typedef _Float16 f16x2 __attribute__((ext_vector_type(2)));

// jax.nn.gelu default is approximate=True (tanh form)
__device__ __forceinline__ float gelu_gamma(float x) {
    const float k0 = 0.7978845608028654f;  // sqrt(2/pi)
    const float k1 = 0.044715f;
    float t = tanhf(k0 * (x + k1 * x * x * x));
    return 0.5f * x * (1.0f + t) * GELU_GAMMA;
}

// Single fused kernel. grid (NB, 2), 1024 threads.
// Wave 0 computes the per-image MLP -> rotation matrix R (barrier-free:
// single-wave DS ops are in-order; __threadfence_block between phases).
// Threads 64..1023 zero the LDS border and stage the fp16 image.
// One __syncthreads, then all 1024 threads gather half the output pixels.
__global__ void __launch_bounds__(1024, 8) retina_fused_kernel(
    const float* __restrict__ stim,   // [NB, 1, IMG_H, IMG_W]
    const float* __restrict__ persp,  // [NB, FDIM]
    const float* __restrict__ W1,     // [FDIM, DDIM]
    const float* __restrict__ b1,     // [DDIM]
    const float* __restrict__ W2,     // [DDIM, DDIM]
    const float* __restrict__ b2,     // [DDIM]
    const float* __restrict__ Wp,     // [DDIM, 3]
    const float* __restrict__ bp,     // [3]
    float* __restrict__ out)          // [NB, 1, IMG_H, IMG_W]
{
    __shared__ __align__(16) _Float16 simg[LDS_ROWS * LDS_STRIDE_H]; // 77,616 B
    __shared__ float shml[2 * DDIM + 12];   // sh1[0..127], sh2[128..255], ang[256..258], R[259..267]

    const int tid  = threadIdx.x;
    const int n    = blockIdx.x;
    const int half = blockIdx.y;

    if (tid < 64) {
        // ================= MLP on wave 0 (no barriers needed) =================
        const int l = tid;
        // layer 1: h1 = gelu(p @ W1 + b1) * gamma ; lane l does outputs l, l+64
        float a0 = b1[l], a1 = b1[l + 64];
#pragma unroll
        for (int f = 0; f < FDIM; ++f) {
            const float pv = persp[n * FDIM + f];
            a0 = fmaf(pv, W1[f * DDIM + l], a0);
            a1 = fmaf(pv, W1[f * DDIM + l + 64], a1);
        }
        shml[l]      = gelu_gamma(a0);
        shml[l + 64] = gelu_gamma(a1);
        __threadfence_block();   // drain ds_writes before same-wave reads

        // layer 2
        float c0 = b2[l], c1 = b2[l + 64];
#pragma unroll 8
        for (int k = 0; k < DDIM; ++k) {
            const float hv = shml[k];
            c0 = fmaf(hv, W2[k * DDIM + l], c0);
            c1 = fmaf(hv, W2[k * DDIM + l + 64], c1);
        }
        shml[DDIM + l]      = gelu_gamma(c0);
        shml[DDIM + l + 64] = gelu_gamma(c1);
        __threadfence_block();

        // head: ang[d] on lanes 0..2
        if (l < 3) {
            float a = bp[l];
#pragma unroll 8
            for (int k = 0; k < DDIM; ++k)
                a = fmaf(shml[DDIM + k], Wp[k * 3 + l], a);
            shml[2 * DDIM + l] = a;   // ang
        }
        __threadfence_block();

        // R = Rz @ Ry @ Rx on lane 0
        if (l == 0) {
            const float ax_ = shml[2 * DDIM + 0];
            const float ay_ = shml[2 * DDIM + 1];
            const float az_ = shml[2 * DDIM + 2];
            const float cx = cosf(ax_), sx = sinf(ax_);
            const float cy = cosf(ay_), sy = sinf(ay_);
            const float cz = cosf(az_), sz = sinf(az_);
            float* R = &shml[2 * DDIM + 3];
            R[0] = cz * cy;  R[1] = cz * sy * sx - sz * cx;  R[2] = cz * sy * cx + sz * sx;
            R[3] = sz * cy;  R[4] = sz * sy * sx + cz * cx;  R[5] = sz * sy * cx - cz * sx;
            R[6] = -sy;      R[7] = cy * sx;                 R[8] = cy * cx;
        }
    } else {
        // ============ border zero + image staging on threads 64..1023 ============
        const int st = tid - 64;           // 0..959

        for (int i = st; i < BORDER_CELLS; i += 960) {
            int idx;
            if (i < 3 * LDS_STRIDE_H) {
                const int r3_ = i / LDS_STRIDE_H;            // 0,1,2
                const int c   = i - r3_ * LDS_STRIDE_H;
                const int r   = (r3_ == 0) ? 0 : (IMG_H + r3_);  // 0,145,146
                idx = r * LDS_STRIDE_H + c;
            } else {
                const int j = i - 3 * LDS_STRIDE_H;          // 0..1151
                const int r = 1 + (j >> 3);                  // 1..144
                int c = j & 7;
                c = (c < 4) ? c : (c + 256);                 // {0..3} / {260..263}
                idx = r * LDS_STRIDE_H + c;
            }
            simg[idx] = (_Float16)0.0f;
        }

        const f32x4* __restrict__ src = (const f32x4*)(stim + (size_t)n * IMG_ELEMS);
#pragma unroll
        for (int p = 0; p < 10; ++p) {
            const int g = st + p * 960;        // f32x4-group index
            if (g < 9216) {
                const int row = g >> 6;        // 64 groups per image row
                const int c4  = g & 63;
                const f16x4 hv = __builtin_convertvector(src[g], f16x4);
                *(f16x4*)&simg[(row + 1) * LDS_STRIDE_H + 4 + c4 * 4] = hv;
            }
        }
    }
    __syncthreads();

    // Rotation matrix from LDS (per-lane VGPR copies; 9 broadcast reads)
    const float r0 = shml[2 * DDIM + 3 + 0], r1 = shml[2 * DDIM + 3 + 1], r2 = shml[2 * DDIM + 3 + 2];
    const float r3 = shml[2 * DDIM + 3 + 3], r4 = shml[2 * DDIM + 3 + 4], r5 = shml[2 * DDIM + 3 + 5];
    const float r6 = shml[2 * DDIM + 3 + 6], r7 = shml[2 * DDIM + 3 + 7], r8 = shml[2 * DDIM + 3 + 8];

    const unsigned* __restrict__ U = (const unsigned*)simg;   // dword view

    // ---- gather: this block covers px [half*18432, half*18432+18432)
#pragma unroll
    for (int p = 0; p < 5; ++p) {
        const int gg = p * 1024 + tid;
        if (gg >= 4608) break;               // wave-uniform tail (tid<512 on p=4)
        const int px0 = half * 18432 + gg * 4;
        const int h   = px0 >> 8;
        const int w0  = px0 & 255;

        // per-row constants
        const float gy  = (2.0f * h + 1.0f - 144.0f) * (1.0f / 256.0f);
        const float ayv = gy * FOV_HALF_RAD;
        const float ay2 = ayv * ayv;
        const float bx = ayv * r1, by = ayv * r4, bz = ayv * r7;

        float wx_[4], wy_[4];
        int dA[4];
        unsigned sh_[4];

#pragma unroll
        for (int j = 0; j < 4; ++j) {
            // ax linear in w
            const float ax = fmaf((float)(w0 + j),
                                  2.0f * FOV_HALF_RAD * (1.0f / 256.0f),
                                  -255.0f * FOV_HALF_RAD * (1.0f / 256.0f));
            const float t = fmaf(ax, ax, ay2);          // a^2, t <= 0.56

            // sinc(a): even Taylor in t
            float sc = fmaf(t, 2.7557319e-6f, -1.9841270e-4f);
            sc = fmaf(t, sc,  8.3333333e-3f);
            sc = fmaf(t, sc, -1.6666667e-1f);
            sc = fmaf(t, sc,  1.0f);

            // cos(a): even Taylor in t
            float ca = fmaf(t, 2.4801587e-5f, -1.3888889e-3f);
            ca = fmaf(t, ca,  4.1666667e-2f);
            ca = fmaf(t, ca, -0.5f);
            ca = fmaf(t, ca,  1.0f);

            const float rx = fmaf(ca, r2, sc * fmaf(ax, r0, bx));
            const float ry = fmaf(ca, r5, sc * fmaf(ax, r3, by));
            const float rz = fmaf(ca, r8, sc * fmaf(ax, r6, bz));

            const float inv = __builtin_amdgcn_rcpf(rz);
            const bool safe = rz > 0.001f;
            const float gxp = safe ? rx * inv : OUT_OF_RANGE;
            const float gyp = safe ? ry * inv : OUT_OF_RANGE;

            // shifted coords: pxs = px+1 in [0,257], pys = py+1 in [0,145]
            const float pxs = __builtin_amdgcn_fmed3f(
                fmaf(gxp, 128.0f, 128.5f), 0.0f, 257.0f);
            const float pys = __builtin_amdgcn_fmed3f(
                fmaf(gyp, 128.0f, 72.5f), 0.0f, 145.0f);

            const int x0s = (int)pxs;        // trunc == floor (>=0)
            const int y0s = (int)pys;
            wx_[j] = pxs - (float)x0s;
            wy_[j] = pys - (float)y0s;

            // half-index of corner00: row y0s, col x0s+3
            const int a00 = y0s * LDS_STRIDE_H + x0s + 3;
            dA[j]  = a00 >> 1;
            sh_[j] = (unsigned)(a00 & 1) << 4;
        }

        // 4 dword reads per px (fuses to ds_read2_b32), issued back-to-back
        unsigned u[16];
#pragma unroll
        for (int j = 0; j < 4; ++j) {
            u[4*j+0] = U[dA[j]];
            u[4*j+1] = U[dA[j] + 1];
            u[4*j+2] = U[dA[j] + 132];    // +1 row (264 halves = 132 dwords)
            u[4*j+3] = U[dA[j] + 133];
        }

        f32x4 res;
#pragma unroll
        for (int j = 0; j < 4; ++j) {
            const unsigned long long t0 =
                ((unsigned long long)u[4*j+1] << 32) | u[4*j+0];
            const unsigned long long t1 =
                ((unsigned long long)u[4*j+3] << 32) | u[4*j+2];
            const f16x2 h0 = __builtin_bit_cast(f16x2, (unsigned)(t0 >> sh_[j]));
            const f16x2 h1 = __builtin_bit_cast(f16x2, (unsigned)(t1 >> sh_[j]));
            const float v00 = (float)h0[0], v01 = (float)h0[1];
            const float v10 = (float)h1[0], v11 = (float)h1[1];
            const float top = fmaf(wx_[j], v01 - v00, v00);
            const float bot = fmaf(wx_[j], v11 - v10, v10);
            res[j] = fmaf(wy_[j], bot - top, top);
        }

        f32x4* dst = (f32x4*)(out + (size_t)n * IMG_ELEMS + px0);
        __builtin_nontemporal_store(res, dst);
    }
}

extern "C" void kernel_launch(void* const* d_in, const int* in_sizes, int n_in,
                              void* d_out, int out_size, void* d_ws, size_t ws_size,
                              hipStream_t stream) {
    const float* stimulus    = (const float*)d_in[0]; // [256,1,144,256]
    const float* perspective = (const float*)d_in[1]; // [256,16]
    const float* W1          = (const float*)d_in[2]; // [16,128]
    const float* b1          = (const float*)d_in[3]; // [128]
    const float* W2          = (const float*)d_in[4]; // [128,128]
    const float* b2          = (const float*)d_in[5]; // [128]
    const float* Wp          = (const float*)d_in[6]; // [128,3]
    const float* bp          = (const float*)d_in[7]; // [3]
    float* out = (float*)d_out;

    dim3 grid(NB, 2);
    retina_fused_kernel<<<grid, 1024, 0, stream>>>(
        stimulus, perspective, W1, b1, W2, b2, Wp, bp, out);
}